// Round 2
// baseline (187.511 us; speedup 1.0000x reference)
//
#include <hip/hip_runtime.h>
#include <hip/hip_bf16.h>

#define D 128  // D_IN == D_OUT == 128

typedef __attribute__((ext_vector_type(8))) short bf16x8;  // 8 bf16 = 4 VGPRs
typedef __attribute__((ext_vector_type(4))) float f32x4;

static __device__ __forceinline__ ushort f2bf(float f) {
    __hip_bfloat16 h = __float2bfloat16(f);  // RNE
    return *(ushort*)&h;
}
static __device__ __forceinline__ float bfl(uint u) { return __uint_as_float(u << 16); }
static __device__ __forceinline__ float bfh(uint u) { return __uint_as_float(u & 0xffff0000u); }

// ---------------- W swizzle: fp32 W[128][128] -> bf16 fragment-order Wz ----------------
// Wz[((ks*8+nb)*64 + lane)*8 + j] = bf16( W[ks*32 + (lane>>4)*8 + j][nb*16 + (lane&15)] )
__global__ __launch_bounds__(256) void swizzle_w(const float* __restrict__ W,
                                                 ushort* __restrict__ Wz)
{
    const int t = blockIdx.x * 256 + threadIdx.x;   // 0..2047 = (combo, lane)
    const int lane = t & 63;
    const int combo = t >> 6;                       // ks*8+nb, 0..31
    const int ks = combo >> 3, nb = combo & 7;
    const int krow = ks * 32 + ((lane >> 4) << 3);
    const int col  = nb * 16 + (lane & 15);
    ushort u[8];
    #pragma unroll
    for (int j = 0; j < 8; ++j) u[j] = f2bf(W[(krow + j) * D + col]);
    uint4 p;
    p.x = (uint)u[0] | ((uint)u[1] << 16);
    p.y = (uint)u[2] | ((uint)u[3] << 16);
    p.z = (uint)u[4] | ((uint)u[5] << 16);
    p.w = (uint)u[6] | ((uint)u[7] << 16);
    *(uint4*)(Wz + (size_t)t * 8) = p;
}

// ---------------- GEMM: Xp'' = bf16( deg[row] * (X @ W) ) via MFMA ----------------
// (unchanged — isolated spmm delta; will surface in top-5 if it is the residual)
__global__ __launch_bounds__(256) void gemm_mfma(const float* __restrict__ X,
                                                 const ushort* __restrict__ Wz,
                                                 const float* __restrict__ deg,
                                                 ushort* __restrict__ Xp, int n)
{
    __shared__ ushort wsh[32 * 64 * 8];   // 32 KB, fragment-order copy of Wz
    const int tid = threadIdx.x;
    {   // stage: 2048 uint4 = 8 per thread, coalesced; lane*16B pattern
        const uint4* src = (const uint4*)Wz;
        uint4* dst = (uint4*)wsh;
        #pragma unroll
        for (int i = 0; i < 8; ++i) dst[tid + i * 256] = src[tid + i * 256];
    }
    __syncthreads();

    const int lane = tid & 63;
    const int wave = tid >> 6;
    const int m = lane & 15, quad = lane >> 4;
    const int r0 = blockIdx.x * 128 + wave * 32;   // 2 tiles: rows r0..r0+15, r0+16..r0+31

    // A-frags: lane holds X[row][ks*32 + quad*8 .. +7] as bf16x8
    bf16x8 afrag[2][4];
    #pragma unroll
    for (int t = 0; t < 2; ++t) {
        long long arow = r0 + t * 16 + m;
        if (arow >= n) arow = n - 1;               // clamp loads; stores guarded
        const float* xa = X + arow * D + quad * 8;
        #pragma unroll
        for (int ks = 0; ks < 4; ++ks) {
            float4 lo = *(const float4*)(xa + ks * 32);
            float4 hi = *(const float4*)(xa + ks * 32 + 4);
            bf16x8 a;
            a[0] = (short)f2bf(lo.x); a[1] = (short)f2bf(lo.y);
            a[2] = (short)f2bf(lo.z); a[3] = (short)f2bf(lo.w);
            a[4] = (short)f2bf(hi.x); a[5] = (short)f2bf(hi.y);
            a[6] = (short)f2bf(hi.z); a[7] = (short)f2bf(hi.w);
            afrag[t][ks] = a;
        }
    }

    f32x4 acc[2][8];
    #pragma unroll
    for (int t = 0; t < 2; ++t)
        #pragma unroll
        for (int nb = 0; nb < 8; ++nb) acc[t][nb] = (f32x4){0.f, 0.f, 0.f, 0.f};

    #pragma unroll
    for (int nb = 0; nb < 8; ++nb) {
        #pragma unroll
        for (int ks = 0; ks < 4; ++ks) {
            bf16x8 b = *(const bf16x8*)(wsh + ((size_t)((ks * 8 + nb) * 64 + lane)) * 8);
            acc[0][nb] = __builtin_amdgcn_mfma_f32_16x16x32_bf16(afrag[0][ks], b, acc[0][nb], 0, 0, 0);
            acc[1][nb] = __builtin_amdgcn_mfma_f32_16x16x32_bf16(afrag[1][ks], b, acc[1][nb], 0, 0, 0);
        }
    }

    // epilogue: fold deg[row], store bf16 (C/D map: row=quad*4+r, col=nb*16+m)
    #pragma unroll
    for (int t = 0; t < 2; ++t) {
        #pragma unroll
        for (int r = 0; r < 4; ++r) {
            const int row = r0 + t * 16 + quad * 4 + r;
            if (row < n) {
                const float dr = deg[row];
                #pragma unroll
                for (int nb = 0; nb < 8; ++nb)
                    Xp[(size_t)row * D + nb * 16 + m] = f2bf(dr * acc[t][nb][r]);
            }
        }
    }
}

// ---------------- SpMM v6: row-run streaming, 2-deep batch pipeline ----------------
// One wave owns ROWS_PER_WAVE consecutive rows and streams their contiguous
// edge range [rp[r0], rp[r0+R]) in full batches of 8 gathers, flushing the
// accumulator at wave-uniform CSR boundaries mid-stream.  Fixes vs v5:
//  - no per-row tail batch (8 wasted gathers/row -> <=1 partial batch/WAVE)
//  - two named batch buffers (vA/vB): batch k+1's 8 gathers are in flight
//    while batch k is accumulated (vmcnt(8), never a full drain)
//  - startup (rp s_load) amortized over ~128 edges instead of ~16
//  - index s_loads stay contiguous s_load_dwordx8 (full-batch fast path)
#define ROWS_PER_WAVE 8

#define ISSUE(V, ebase, cnt)                                              \
    do {                                                                  \
        int _rem = eend - (ebase);                                        \
        (cnt) = _rem > 8 ? 8 : _rem;                                      \
        int _c[8];                                                        \
        if ((cnt) == 8) {            /* contiguous -> s_load_dwordx8 */   \
            _Pragma("unroll")                                             \
            for (int _j = 0; _j < 8; ++_j) _c[_j] = ci[(ebase) + _j];     \
        } else {                     /* tail: clamp (dups hit L1) */      \
            _Pragma("unroll")                                             \
            for (int _j = 0; _j < 8; ++_j)                                \
                _c[_j] = ci[(ebase) + (_j < (cnt) ? _j : 0)];             \
        }                                                                 \
        _Pragma("unroll")                                                 \
        for (int _j = 0; _j < 8; ++_j)                                    \
            V[_j] = Xq[(size_t)_c[_j] * 64 + lane];                       \
    } while (0)

// accumulate one batch, flushing rows at CSR boundaries (all wave-uniform)
#define ACCUM(V, ebase, cnt)                                              \
    do {                                                                  \
        _Pragma("unroll")                                                 \
        for (int _j = 0; _j < 8; ++_j) {                                  \
            if (_j < (cnt)) {                                             \
                while ((ebase) + _j >= bnd) {   /* flush current row */   \
                    const float _dr = deg[row];                           \
                    float2 _o;                                            \
                    _o.x = _dr * (a0 + b0);                               \
                    _o.y = _dr * (a1 + b1);                               \
                    *(float2*)(out + (size_t)row * D + lane * 2) = _o;    \
                    a0 = a1 = b0 = b1 = 0.f;                              \
                    ++row;                                                \
                    bnd = rp[row + 1];                                    \
                }                                                         \
                if (_j & 1) { b0 += bfl(V[_j]); b1 += bfh(V[_j]); }       \
                else        { a0 += bfl(V[_j]); a1 += bfh(V[_j]); }       \
            }                                                             \
        }                                                                 \
    } while (0)

__global__ __launch_bounds__(256) void spmm_csr(const ushort* __restrict__ Xp,
                                                const float* __restrict__ deg,
                                                const int* __restrict__ rp,
                                                const int* __restrict__ ci,
                                                float* __restrict__ out, int n)
{
    const int r0 = __builtin_amdgcn_readfirstlane(
        (blockIdx.x * 4 + (threadIdx.x >> 6)) * ROWS_PER_WAVE);
    if (r0 >= n) return;                              // uniform whole-wave exit
    const int rend = (r0 + ROWS_PER_WAVE < n) ? r0 + ROWS_PER_WAVE : n;
    const int lane = threadIdx.x & 63;
    const uint* __restrict__ Xq = (const uint*)Xp;    // one bf16 row = 64 uints

    int e    = rp[r0];                                // uniform -> s_load
    const int eend = rp[rend];
    int row  = r0;
    int bnd  = rp[row + 1];

    float a0 = 0.f, a1 = 0.f, b0 = 0.f, b1 = 0.f;     // parity-split accums

    uint vA[8], vB[8];
    int eA = e, cntA = 0;
    if (eA < eend) { ISSUE(vA, eA, cntA); e = eA + cntA; }
    int eB = e, cntB = 0;
    if (eB < eend) { ISSUE(vB, eB, cntB); e = eB + cntB; }

    for (;;) {
        if (cntA == 0) break;
        ACCUM(vA, eA, cntA);
        eA = e; cntA = 0;
        if (eA < eend) { ISSUE(vA, eA, cntA); e = eA + cntA; }
        if (cntB == 0) break;
        ACCUM(vB, eB, cntB);
        eB = e; cntB = 0;
        if (eB < eend) { ISSUE(vB, eB, cntB); e = eB + cntB; }
    }

    // flush remaining rows (current accumulated row + trailing empty rows)
    while (row < rend) {
        const float dr = deg[row];
        float2 o;
        o.x = dr * (a0 + b0);
        o.y = dr * (a1 + b1);
        *(float2*)(out + (size_t)row * D + lane * 2) = o;
        a0 = a1 = b0 = b1 = 0.f;
        ++row;
    }
}

extern "C" void kernel_launch(void* const* d_in, const int* in_sizes, int n_in,
                              void* d_out, int out_size, void* d_ws, size_t ws_size,
                              hipStream_t stream)
{
    const float* X   = (const float*)d_in[0];   // [N,128] fp32
    const float* W   = (const float*)d_in[1];   // [128,128] fp32
    const float* deg = (const float*)d_in[2];   // [N] fp32
    const int*   rp  = (const int*)d_in[3];     // [N+1] int32
    const int*   ci  = (const int*)d_in[4];     // [E] int32
    float* out = (float*)d_out;                 // [N,128] fp32
    const int n = in_sizes[2];                  // N = 100000

    ushort* Xp = (ushort*)d_ws;                 // X'' bf16: n*128*2 = 25.6 MB
    ushort* Wz = Xp + (size_t)n * D;            // swizzled bf16 W: 32 KB

    const int waves  = (n + ROWS_PER_WAVE - 1) / ROWS_PER_WAVE;
    const int blocks = (waves + 3) / 4;

    swizzle_w<<<8, 256, 0, stream>>>(W, Wz);
    gemm_mfma<<<(n + 127) / 128, 256, 0, stream>>>(X, Wz, deg, Xp, n);
    spmm_csr<<<blocks, 256, 0, stream>>>(Xp, deg, rp, ci, out, n);
}

// Round 3
// 176.325 us; speedup vs baseline: 1.0634x; 1.0634x over previous
//
#include <hip/hip_runtime.h>
#include <hip/hip_bf16.h>

#define D 128  // D_IN == D_OUT == 128

typedef __attribute__((ext_vector_type(8))) short bf16x8;  // 8 bf16 = 4 VGPRs
typedef __attribute__((ext_vector_type(4))) float f32x4;

static __device__ __forceinline__ ushort f2bf(float f) {
    __hip_bfloat16 h = __float2bfloat16(f);  // RNE
    return *(ushort*)&h;
}
static __device__ __forceinline__ float bfl(uint u) { return __uint_as_float(u << 16); }
static __device__ __forceinline__ float bfh(uint u) { return __uint_as_float(u & 0xffff0000u); }

// ---------------- W swizzle: fp32 W[128][128] -> bf16 fragment-order Wz ----------------
// Wz[((ks*8+nb)*64 + lane)*8 + j] = bf16( W[ks*32 + (lane>>4)*8 + j][nb*16 + (lane&15)] )
__global__ __launch_bounds__(256) void swizzle_w(const float* __restrict__ W,
                                                 ushort* __restrict__ Wz)
{
    const int t = blockIdx.x * 256 + threadIdx.x;   // 0..2047 = (combo, lane)
    const int lane = t & 63;
    const int combo = t >> 6;                       // ks*8+nb, 0..31
    const int ks = combo >> 3, nb = combo & 7;
    const int krow = ks * 32 + ((lane >> 4) << 3);
    const int col  = nb * 16 + (lane & 15);
    ushort u[8];
    #pragma unroll
    for (int j = 0; j < 8; ++j) u[j] = f2bf(W[(krow + j) * D + col]);
    uint4 p;
    p.x = (uint)u[0] | ((uint)u[1] << 16);
    p.y = (uint)u[2] | ((uint)u[3] << 16);
    p.z = (uint)u[4] | ((uint)u[5] << 16);
    p.w = (uint)u[6] | ((uint)u[7] << 16);
    *(uint4*)(Wz + (size_t)t * 8) = p;
}

// ---------------- GEMM v3: swapped-operand MFMA -> contiguous-col epilogue ----------------
// mfma(Wfrag as A, Xfrag as B) computes (X·W)^T per tile (A/B frag layouts are
// row/col-symmetric), so the fixed C/D map (col=lane&15, row=quad*4+reg) gives
// each lane row = r0+t*16+m with FOUR CONSECUTIVE cols nb*16+quad*4+{0..3}.
// Epilogue: pack 4 bf16 -> uint2, 16 stores/lane (was 64 scalar 2B stores),
// 512B contiguous per wave-instr (was 128B scattered). No LDS bounce needed.
__global__ __launch_bounds__(256) void gemm_mfma(const float* __restrict__ X,
                                                 const ushort* __restrict__ Wz,
                                                 const float* __restrict__ deg,
                                                 ushort* __restrict__ Xp, int n)
{
    __shared__ ushort wsh[32 * 64 * 8];   // 32 KB, fragment-order copy of Wz
    const int tid = threadIdx.x;
    {   // stage: 2048 uint4 = 8 per thread, coalesced
        const uint4* src = (const uint4*)Wz;
        uint4* dst = (uint4*)wsh;
        #pragma unroll
        for (int i = 0; i < 8; ++i) dst[tid + i * 256] = src[tid + i * 256];
    }
    __syncthreads();

    const int lane = tid & 63;
    const int wave = tid >> 6;
    const int m = lane & 15, quad = lane >> 4;
    const int r0 = blockIdx.x * 128 + wave * 32;   // 2 tiles: rows r0..r0+15, r0+16..r0+31

    // X-frags: lane holds X[r0+t*16+m][ks*32 + quad*8 .. +7] as bf16x8
    // (same layout as before; now fed as the *B* operand of the swapped MFMA)
    bf16x8 xfrag[2][4];
    #pragma unroll
    for (int t = 0; t < 2; ++t) {
        long long arow = r0 + t * 16 + m;
        if (arow >= n) arow = n - 1;               // clamp loads; stores guarded
        const float* xa = X + arow * D + quad * 8;
        #pragma unroll
        for (int ks = 0; ks < 4; ++ks) {
            float4 lo = *(const float4*)(xa + ks * 32);
            float4 hi = *(const float4*)(xa + ks * 32 + 4);
            bf16x8 a;
            a[0] = (short)f2bf(lo.x); a[1] = (short)f2bf(lo.y);
            a[2] = (short)f2bf(lo.z); a[3] = (short)f2bf(lo.w);
            a[4] = (short)f2bf(hi.x); a[5] = (short)f2bf(hi.y);
            a[6] = (short)f2bf(hi.z); a[7] = (short)f2bf(hi.w);
            xfrag[t][ks] = a;
        }
    }

    f32x4 acc[2][8];
    #pragma unroll
    for (int t = 0; t < 2; ++t)
        #pragma unroll
        for (int nb = 0; nb < 8; ++nb) acc[t][nb] = (f32x4){0.f, 0.f, 0.f, 0.f};

    #pragma unroll
    for (int nb = 0; nb < 8; ++nb) {
        #pragma unroll
        for (int ks = 0; ks < 4; ++ks) {
            bf16x8 w = *(const bf16x8*)(wsh + ((size_t)((ks * 8 + nb) * 64 + lane)) * 8);
            // swapped operands: D = (W^T tile)·(X^T tile) = (X·W)^T tile
            acc[0][nb] = __builtin_amdgcn_mfma_f32_16x16x32_bf16(w, xfrag[0][ks], acc[0][nb], 0, 0, 0);
            acc[1][nb] = __builtin_amdgcn_mfma_f32_16x16x32_bf16(w, xfrag[1][ks], acc[1][nb], 0, 0, 0);
        }
    }

    // epilogue: lane holds Xp[row = r0+t*16+m][cols nb*16+quad*4+{0..3}]
    #pragma unroll
    for (int t = 0; t < 2; ++t) {
        const int row = r0 + t * 16 + m;
        if (row < n) {
            const float dr = deg[row];
            ushort* dstrow = Xp + (size_t)row * D + quad * 4;
            #pragma unroll
            for (int nb = 0; nb < 8; ++nb) {
                uint2 p;
                p.x = (uint)f2bf(dr * acc[t][nb][0]) | ((uint)f2bf(dr * acc[t][nb][1]) << 16);
                p.y = (uint)f2bf(dr * acc[t][nb][2]) | ((uint)f2bf(dr * acc[t][nb][3]) << 16);
                *(uint2*)(dstrow + nb * 16) = p;   // 8B store, 4 consecutive cols
            }
        }
    }
}

// ---------------- SpMM v5 (revert, known 66 µs): one wave per row, scalar index stream ----------------
// At the structural wall: dur ~= (FETCH 185MB + WRITE 50MB)/3.6 TB/s; the fetch
// is the compulsory per-XCD L2-fill floor for a 25.6MB random-gather table.
__global__ __launch_bounds__(256) void spmm_csr(const ushort* __restrict__ Xp,
                                                const float* __restrict__ deg,
                                                const int* __restrict__ rp,
                                                const int* __restrict__ ci,
                                                float* __restrict__ out, int n)
{
    int row = __builtin_amdgcn_readfirstlane(blockIdx.x * 4 + (threadIdx.x >> 6));
    if (row >= n) row = n - 1;            // uniform clamp (n%4==0: never taken)
    const int lane = threadIdx.x & 63;
    const int beg = rp[row];              // uniform -> s_load
    const int end = rp[row + 1];
    const uint* __restrict__ Xq = (const uint*)Xp;   // one bf16 row = 64 uints

    float a0 = 0.f, a1 = 0.f;             // parity-split accumulator pairs
    float b0 = 0.f, b1 = 0.f;

    int e = beg;
    for (; e + 8 <= end; e += 8) {
        const int c0 = ci[e + 0], c1 = ci[e + 1], c2 = ci[e + 2], c3 = ci[e + 3];
        const int c4 = ci[e + 4], c5 = ci[e + 5], c6 = ci[e + 6], c7 = ci[e + 7];
        const uint v0 = Xq[(size_t)c0 * 64 + lane];
        const uint v1 = Xq[(size_t)c1 * 64 + lane];
        const uint v2 = Xq[(size_t)c2 * 64 + lane];
        const uint v3 = Xq[(size_t)c3 * 64 + lane];
        const uint v4 = Xq[(size_t)c4 * 64 + lane];
        const uint v5 = Xq[(size_t)c5 * 64 + lane];
        const uint v6 = Xq[(size_t)c6 * 64 + lane];
        const uint v7 = Xq[(size_t)c7 * 64 + lane];
        a0 += bfl(v0); a1 += bfh(v0);
        b0 += bfl(v1); b1 += bfh(v1);
        a0 += bfl(v2); a1 += bfh(v2);
        b0 += bfl(v3); b1 += bfh(v3);
        a0 += bfl(v4); a1 += bfh(v4);
        b0 += bfl(v5); b1 += bfh(v5);
        a0 += bfl(v6); a1 += bfh(v6);
        b0 += bfl(v7); b1 += bfh(v7);
    }

    if (e < end) {                         // clamped tail batch, still 8-deep
        int cc[8];
        #pragma unroll
        for (int j = 0; j < 8; ++j) {
            const int ee = e + j;
            cc[j] = ci[ee < end ? ee : end - 1];
        }
        uint vv[8];
        #pragma unroll
        for (int j = 0; j < 8; ++j) vv[j] = Xq[(size_t)cc[j] * 64 + lane];
        #pragma unroll
        for (int j = 0; j < 8; ++j) {
            if (e + j < end) {
                a0 += bfl(vv[j]); a1 += bfh(vv[j]);
            }
        }
    }

    const float dr = deg[row];             // uniform -> s_load
    float2 o;
    o.x = dr * (a0 + b0);
    o.y = dr * (a1 + b1);
    *(float2*)(out + (size_t)row * D + lane * 2) = o;   // coalesced
}

extern "C" void kernel_launch(void* const* d_in, const int* in_sizes, int n_in,
                              void* d_out, int out_size, void* d_ws, size_t ws_size,
                              hipStream_t stream)
{
    const float* X   = (const float*)d_in[0];   // [N,128] fp32
    const float* W   = (const float*)d_in[1];   // [128,128] fp32
    const float* deg = (const float*)d_in[2];   // [N] fp32
    const int*   rp  = (const int*)d_in[3];     // [N+1] int32
    const int*   ci  = (const int*)d_in[4];     // [E] int32
    float* out = (float*)d_out;                 // [N,128] fp32
    const int n = in_sizes[2];                  // N = 100000

    ushort* Xp = (ushort*)d_ws;                 // X'' bf16: n*128*2 = 25.6 MB
    ushort* Wz = Xp + (size_t)n * D;            // swizzled bf16 W: 32 KB

    swizzle_w<<<8, 256, 0, stream>>>(W, Wz);
    gemm_mfma<<<(n + 127) / 128, 256, 0, stream>>>(X, Wz, deg, Xp, n);
    spmm_csr<<<(n + 3) / 4, 256, 0, stream>>>(Xp, deg, rp, ci, out, n);
}